// Round 16
// baseline (430.732 us; speedup 1.0000x reference)
//
#include <hip/hip_runtime.h>
#include <hip/hip_bf16.h>

#define S 2048
#define D 1024
#define NE 8
#define HF 4096
#define HH 8192
#define BK 32
#define ACT_ROWS 4224  // 4096 + 128 pad
#define MAXRB 40       // 128-row blocks: 4096/128 + 8 - 1 = 39
#define MAXRB2 24      // 256-row blocks: 4096/256 + 8 - 1 = 23

typedef __attribute__((ext_vector_type(8))) __bf16 bf16x8;
typedef __attribute__((ext_vector_type(4))) float f32x4;

__device__ __forceinline__ unsigned cvtpk(float lo, float hi) {
  unsigned r;
  asm("v_cvt_pk_bf16_f32 %0, %1, %2" : "=v"(r) : "v"(lo), "v"(hi));
  return r;  // RNE, lo in low 16
}
__device__ __forceinline__ unsigned bf16b(float f) {
  unsigned b = __float_as_uint(f);
  return (b + 0x7fffu + ((b >> 16) & 1u)) >> 16;  // RNE fp32->bf16 (finite)
}

// ------- gating + x->bf16 fused: one block (256 thr) per token -------
__global__ __launch_bounds__(256) void gate_kernel(
    const float* __restrict__ x, const float* __restrict__ gw,
    const float* __restrict__ gb, ushort* __restrict__ xb,
    int* __restrict__ mi0, int* __restrict__ mi1,
    float* __restrict__ mw0, float* __restrict__ mw1) {
  const int t = blockIdx.x;
  const int l = threadIdx.x;  // handles d = 4l..4l+3
  const float4 xv = ((const float4*)(x + (size_t)t * D))[l];
  uint2 wv = {cvtpk(xv.x, xv.y), cvtpk(xv.z, xv.w)};
  ((uint2*)(xb + (size_t)t * D))[l] = wv;

  float xa[4] = {xv.x, xv.y, xv.z, xv.w};
  float acc[NE];
#pragma unroll
  for (int e = 0; e < NE; ++e) acc[e] = 0.f;
  const float* g0 = gw + (size_t)(4 * l) * NE;
#pragma unroll
  for (int j = 0; j < 4; ++j)
#pragma unroll
    for (int e = 0; e < NE; ++e) acc[e] += xa[j] * g0[j * NE + e];
#pragma unroll
  for (int e = 0; e < NE; ++e) {
    float v = acc[e];
#pragma unroll
    for (int off = 32; off > 0; off >>= 1) v += __shfl_xor(v, off);
    acc[e] = v;
  }
  __shared__ float sm[4][NE];
  const int wid = l >> 6;
  if ((l & 63) == 0) {
#pragma unroll
    for (int e = 0; e < NE; ++e) sm[wid][e] = acc[e];
  }
  __syncthreads();
  if (l == 0) {
    float lg[NE];
#pragma unroll
    for (int e = 0; e < NE; ++e)
      lg[e] = sm[0][e] + sm[1][e] + sm[2][e] + sm[3][e] + gb[e];
    int i0 = 0; float m0 = lg[0];
#pragma unroll
    for (int e = 1; e < NE; ++e) if (lg[e] > m0) { m0 = lg[e]; i0 = e; }  // strict >: jax tie-break
    int i1 = -1; float m1 = -3.4e38f;
#pragma unroll
    for (int e = 0; e < NE; ++e) if (e != i0 && lg[e] > m1) { m1 = lg[e]; i1 = e; }
    float p = __expf(m1 - m0);
    float inv = 1.f / (1.f + p);
    mi0[t] = i0; mi1[t] = i1;
    mw0[t] = inv; mw1[t] = p * inv;
  }
}

// --- routing: counts + prefix + slots + compact rowblock tables (128 & 256 gran) ---
__global__ __launch_bounds__(1024) void route_kernel(
    const int* __restrict__ mi0, const int* __restrict__ mi1,
    int* __restrict__ counts, int* __restrict__ basep, int* __restrict__ list_tok,
    int* __restrict__ mr0, int* __restrict__ mr1,
    int* __restrict__ rb_e, int* __restrict__ rb_row0, int* __restrict__ rb_n,
    int* __restrict__ rb2_e, int* __restrict__ rb2_row0, int* __restrict__ rb2_n) {
  __shared__ int cnt[NE];
  __shared__ int cur[NE];
  const int t = threadIdx.x;
  if (t < NE) cnt[t] = 0;
  __syncthreads();
  const int e0a = mi0[t], e1a = mi1[t];
  const int e0b = mi0[t + 1024], e1b = mi1[t + 1024];
  atomicAdd(&cnt[e0a], 1); atomicAdd(&cnt[e1a], 1);
  atomicAdd(&cnt[e0b], 1); atomicAdd(&cnt[e1b], 1);
  __syncthreads();
  if (t == 0) {
    int s = 0;
#pragma unroll
    for (int e = 0; e < NE; ++e) { basep[e] = s; cur[e] = s; s += cnt[e]; }
    basep[NE] = s;
    int nrb = 0, nrb2 = 0;
    for (int e = 0; e < NE; ++e) {
      for (int r0 = 0; r0 < cnt[e]; r0 += 128) {
        rb_e[nrb] = e; rb_row0[nrb] = r0; ++nrb;
      }
      for (int r0 = 0; r0 < cnt[e]; r0 += 256) {
        rb2_e[nrb2] = e; rb2_row0[nrb2] = r0; ++nrb2;
      }
    }
    *rb_n = nrb;    // <= 39
    *rb2_n = nrb2;  // <= 23
  }
  if (t < NE) counts[t] = cnt[t];
  __syncthreads();
  int r;
  r = atomicAdd(&cur[e0a], 1); list_tok[r] = t; mr0[t] = r;
  r = atomicAdd(&cur[e1a], 1); list_tok[r] = t; mr1[t] = r;
  r = atomicAdd(&cur[e0b], 1); list_tok[r] = t + 1024; mr0[t + 1024] = r;
  r = atomicAdd(&cur[e1b], 1); list_tok[r] = t + 1024; mr1[t + 1024] = r;
}

// ---- GEMM1 + SwiGLU, BM=256, 8 waves: A per-wave-private -> direct global->reg ----
// (A rows are never shared across waves; LDS holds only B.  LDS traffic/wave/K-step
//  drops 11KB -> 5KB; no global_load_lds left -> barrier vmcnt-drain cheap.)
#define G1_STEP(AFUSE, AFLOAD, IT, CUR)                                        \
  {                                                                            \
    const bool pf = ((IT) + 1 < D / BK);                                       \
    float4 b0v, b1v;                                                           \
    if (pf) {                                                                  \
      const size_t koff = (size_t)((IT) + 1) * BK;                             \
      b0v = *(const float4*)(pB + koff * HH);                                  \
      b1v = *(const float4*)(pB + koff * HH + HH);                             \
      _Pragma("unroll")                                                        \
      for (int mi = 0; mi < 4; ++mi)                                           \
        AFLOAD[mi] = *(const uint4*)(pA[mi] + koff);                           \
    }                                                                          \
    bf16x8 bfr[2][2];                                                          \
    _Pragma("unroll")                                                          \
    for (int h = 0; h < 2; ++h)                                                \
      _Pragma("unroll")                                                        \
      for (int ni = 0; ni < 2; ++ni) {                                         \
        const int col = wn + ni * 16 + lr;                                     \
        uint4 tv;                                                              \
        tv.x = Bs[CUR][h * 16 + kg * 4 + 0][col];                              \
        tv.y = Bs[CUR][h * 16 + kg * 4 + 1][col];                              \
        tv.z = Bs[CUR][h * 16 + kg * 4 + 2][col];                              \
        tv.w = Bs[CUR][h * 16 + kg * 4 + 3][col];                              \
        bfr[h][ni] = *(const bf16x8*)&tv;                                      \
      }                                                                        \
    _Pragma("unroll")                                                          \
    for (int h = 0; h < 2; ++h)                                                \
      _Pragma("unroll")                                                        \
      for (int mi = 0; mi < 4; ++mi)                                           \
        _Pragma("unroll")                                                      \
        for (int ni = 0; ni < 2; ++ni)                                         \
          acc[h][mi][ni] = __builtin_amdgcn_mfma_f32_16x16x32_bf16(            \
              *(const bf16x8*)&AFUSE[mi], bfr[h][ni], acc[h][mi][ni], 0, 0, 0);\
    if (pf) {                                                                  \
      uint4 u = {cvtpk(b0v.x, b1v.x), cvtpk(b0v.y, b1v.y),                     \
                 cvtpk(b0v.z, b1v.z), cvtpk(b0v.w, b1v.w)};                    \
      *(uint4*)&Bs[(CUR) ^ 1][half * 16 + kp][n4] = u;                         \
    }                                                                          \
    __syncthreads();                                                           \
  }

__global__ __launch_bounds__(512) void gemm1_kernel(
    const ushort* __restrict__ xb, const float* __restrict__ w1,
    const float* __restrict__ b1, const int* __restrict__ counts,
    const int* __restrict__ basep, const int* __restrict__ list_tok,
    const int* __restrict__ rb2_e, const int* __restrict__ rb2_row0,
    const int* __restrict__ rb2_n, ushort* __restrict__ act_buf) {
  const int rb = blockIdx.y;
  if (rb >= *rb2_n) return;
  const int e = rb2_e[rb];
  const int row0 = rb2_row0[rb];
  const int cnt = counts[e];
  const int jt = blockIdx.x * 64;
  const float* __restrict__ Wf = w1 + (size_t)e * D * HH;  // [k=1024][n=8192] fp32
  const int gbase = basep[e];

  __shared__ unsigned Bs[2][32][68];  // [half*16+kp][n 0..63, +4 pad]

  const int tid = threadIdx.x;
  const int w = tid >> 6;   // 0..7
  const int i = tid & 63;
  const int lr = i & 15;
  const int kg = i >> 4;            // 0..3
  const int wm = (w >> 1) * 64;     // 0,64,128,192
  const int wn = (w & 1) * 32;

  // A: per-lane token-row pointers (loop-invariant); lane reads 16B at kg*8
  const ushort* pA[4];
#pragma unroll
  for (int mi = 0; mi < 4; ++mi) {
    int rr = row0 + wm + mi * 16 + lr;
    int ss = (rr < cnt) ? rr : cnt - 1;
    pA[mi] = xb + (size_t)list_tok[gbase + ss] * D + kg * 8;
  }

  // B staging: thread = (half, kpair kp, n4..n4+3); 2 coalesced float4 loads
  const int half = tid >> 8;        // 0: x-half, 1: gate-half
  const int kp = (tid >> 4) & 15;   // 0..15
  const int n4 = (tid & 15) * 4;    // 0..60
  const float* pB = Wf + (size_t)(2 * kp) * HH + jt + n4 + half * HF;

  f32x4 acc[2][4][2] = {};  // [half][mi][ni]
  uint4 afA[4], afB[4];

  // prologue: stage B tile 0, load A tile 0
  {
    float4 b0v = *(const float4*)(pB);
    float4 b1v = *(const float4*)(pB + HH);
    uint4 u = {cvtpk(b0v.x, b1v.x), cvtpk(b0v.y, b1v.y),
               cvtpk(b0v.z, b1v.z), cvtpk(b0v.w, b1v.w)};
    *(uint4*)&Bs[0][half * 16 + kp][n4] = u;
  }
#pragma unroll
  for (int mi = 0; mi < 4; ++mi) afA[mi] = *(const uint4*)(pA[mi]);
  __syncthreads();

#pragma unroll 1
  for (int it = 0; it < D / BK; it += 2) {
    G1_STEP(afA, afB, it, 0);
    G1_STEP(afB, afA, it + 1, 1);
  }

#pragma unroll
  for (int mi = 0; mi < 4; ++mi)
#pragma unroll
    for (int ni = 0; ni < 2; ++ni) {
      const int c = jt + wn + ni * 16 + lr;
      const float bx = b1[(size_t)e * HH + c];
      const float bg = b1[(size_t)e * HH + HF + c];
      f32x4 vx = acc[0][mi][ni];
      f32x4 vg = acc[1][mi][ni];
#pragma unroll
      for (int q = 0; q < 4; ++q) {
        const int slot = row0 + wm + mi * 16 + kg * 4 + q;
        if (slot < cnt) {
          float xv = vx[q] + bx;
          float g = vg[q] + bg;
          float a = g / (1.f + __expf(-g)) * xv;
          act_buf[(size_t)(gbase + slot) * HF + c] = (ushort)bf16b(a);
        }
      }
    }
}

// ---- GEMM2 (K-split 2): A direct global->reg, B via LDS (unchanged layout) ----
#define G2_STEP(AFUSE, AFLOAD, IT, CUR)                                        \
  {                                                                            \
    const bool pf = ((IT) + 1 < (HF / 2) / BK);                                \
    float4 a0, a1, c0, c1;                                                     \
    if (pf) {                                                                  \
      const size_t koff = (size_t)((IT) + 1) * BK;                             \
      a0 = *(const float4*)(pB0 + koff * D);                                   \
      a1 = *(const float4*)(pB0 + koff * D + D);                               \
      c0 = *(const float4*)(pB1 + koff * D);                                   \
      c1 = *(const float4*)(pB1 + koff * D + D);                               \
      _Pragma("unroll")                                                        \
      for (int mi = 0; mi < 4; ++mi)                                           \
        AFLOAD[mi] = *(const uint4*)(pA[mi] + koff);                           \
    }                                                                          \
    bf16x8 bfr[4];                                                             \
    _Pragma("unroll")                                                          \
    for (int ni = 0; ni < 4; ++ni) {                                           \
      const int col = wn + ni * 16 + lr;                                       \
      uint4 tv;                                                                \
      tv.x = Bs[CUR][kg * 4 + 0][col];                                         \
      tv.y = Bs[CUR][kg * 4 + 1][col];                                         \
      tv.z = Bs[CUR][kg * 4 + 2][col];                                         \
      tv.w = Bs[CUR][kg * 4 + 3][col];                                         \
      bfr[ni] = *(const bf16x8*)&tv;                                           \
    }                                                                          \
    _Pragma("unroll")                                                          \
    for (int mi = 0; mi < 4; ++mi)                                             \
      _Pragma("unroll")                                                        \
      for (int ni = 0; ni < 4; ++ni)                                           \
        acc[mi][ni] = __builtin_amdgcn_mfma_f32_16x16x32_bf16(                 \
            *(const bf16x8*)&AFUSE[mi], bfr[ni], acc[mi][ni], 0, 0, 0);        \
    if (pf) {                                                                  \
      uint4 u0 = {cvtpk(a0.x, a1.x), cvtpk(a0.y, a1.y),                        \
                  cvtpk(a0.z, a1.z), cvtpk(a0.w, a1.w)};                       \
      uint4 u1 = {cvtpk(c0.x, c1.x), cvtpk(c0.y, c1.y),                        \
                  cvtpk(c0.z, c1.z), cvtpk(c0.w, c1.w)};                       \
      *(uint4*)&Bs[(CUR) ^ 1][grp][n4] = u0;                                   \
      *(uint4*)&Bs[(CUR) ^ 1][8 + grp][n4] = u1;                               \
    }                                                                          \
    __syncthreads();                                                           \
  }

__global__ __launch_bounds__(256) void gemm2_kernel(
    const ushort* __restrict__ act_buf, const float* __restrict__ w2,
    const int* __restrict__ counts, const int* __restrict__ basep,
    const int* __restrict__ rb_e, const int* __restrict__ rb_row0,
    const int* __restrict__ rb_n, ushort* __restrict__ oe) {
  const int rb = blockIdx.y;
  if (rb >= *rb_n) return;
  const int e = rb_e[rb];
  const int row0 = rb_row0[rb];
  const int cnt = counts[e];
  const int split = blockIdx.z;
  const int jt = blockIdx.x * 128;
  const float* __restrict__ Wf = w2 + (size_t)e * HF * D;  // [kf=4096][n=1024] fp32
  const int gbase = basep[e];
  const size_t kbase = (size_t)split * (HF / 2);

  __shared__ unsigned Bs[2][16][132];  // [kp][n 0..127, +4 pad]

  const int tid = threadIdx.x;
  const int w = tid >> 6;
  const int i = tid & 63;
  const int lr = i & 15;
  const int kg = i >> 4;
  const int wm = (w >> 1) * 64;
  const int wn = (w & 1) * 64;

  // A: per-lane act-row pointers (contiguous rows; rows >= cnt read stale finite data,
  // their outputs are discarded by the slot<cnt guard — same as prior gll16 behavior)
  const ushort* pA[4];
#pragma unroll
  for (int mi = 0; mi < 4; ++mi)
    pA[mi] = act_buf + (size_t)(gbase + row0 + wm + mi * 16 + lr) * HF + kbase + kg * 8;

  // B staging: thread = (kpairs grp & grp+8, n4..n4+3)
  const int grp = tid >> 5;          // 0..7
  const int n4 = (tid & 31) * 4;     // 0..124
  const float* pB0 = Wf + (kbase + 2 * grp) * D + jt + n4;  // kp = grp
  const float* pB1 = pB0 + (size_t)16 * D;                   // kp = grp + 8

  f32x4 acc[4][4] = {};
  uint4 afA[4], afB[4];

  {
    float4 a0 = *(const float4*)(pB0);
    float4 a1 = *(const float4*)(pB0 + D);
    float4 c0 = *(const float4*)(pB1);
    float4 c1 = *(const float4*)(pB1 + D);
    uint4 u0 = {cvtpk(a0.x, a1.x), cvtpk(a0.y, a1.y), cvtpk(a0.z, a1.z), cvtpk(a0.w, a1.w)};
    uint4 u1 = {cvtpk(c0.x, c1.x), cvtpk(c0.y, c1.y), cvtpk(c0.z, c1.z), cvtpk(c0.w, c1.w)};
    *(uint4*)&Bs[0][grp][n4] = u0;
    *(uint4*)&Bs[0][8 + grp][n4] = u1;
  }
#pragma unroll
  for (int mi = 0; mi < 4; ++mi) afA[mi] = *(const uint4*)(pA[mi]);
  __syncthreads();

#pragma unroll 1
  for (int it = 0; it < (HF / 2) / BK; it += 2) {
    G2_STEP(afA, afB, it, 0);
    G2_STEP(afB, afA, it + 1, 1);
  }

#pragma unroll
  for (int mi = 0; mi < 4; ++mi)
#pragma unroll
    for (int ni = 0; ni < 4; ++ni) {
      f32x4 v = acc[mi][ni];
#pragma unroll
      for (int q = 0; q < 4; ++q) {
        const int slot = row0 + wm + mi * 16 + kg * 4 + q;
        if (slot < cnt)
          oe[((size_t)split * ACT_ROWS + gbase + slot) * D + jt + wn + ni * 16 + lr] =
              (ushort)bf16b(v[q]);
      }
    }
}

// ---- combine: out[t] = w0*(sum_s oe[s][r0] + b2[e0]) + w1*(sum_s oe[s][r1] + b2[e1]) ----
__global__ void combine_kernel(const ushort* __restrict__ oe,
                               const int* __restrict__ mr0, const int* __restrict__ mr1,
                               const float* __restrict__ mw0, const float* __restrict__ mw1,
                               const int* __restrict__ mi0, const int* __restrict__ mi1,
                               const float* __restrict__ b2, float* __restrict__ out) {
  const int t = blockIdx.x;
  const int l = threadIdx.x;  // 4 elems per thread
  const float w0 = mw0[t], w1 = mw1[t];
  const int r0 = mr0[t], r1 = mr1[t];
  float a0[4] = {0.f, 0.f, 0.f, 0.f}, a1[4] = {0.f, 0.f, 0.f, 0.f};
#pragma unroll
  for (int s = 0; s < 2; ++s) {
    uint2 u0 = *(const uint2*)(oe + ((size_t)s * ACT_ROWS + r0) * D + l * 4);
    uint2 u1 = *(const uint2*)(oe + ((size_t)s * ACT_ROWS + r1) * D + l * 4);
    a0[0] += __uint_as_float(u0.x << 16);
    a0[1] += __uint_as_float(u0.x & 0xffff0000u);
    a0[2] += __uint_as_float(u0.y << 16);
    a0[3] += __uint_as_float(u0.y & 0xffff0000u);
    a1[0] += __uint_as_float(u1.x << 16);
    a1[1] += __uint_as_float(u1.x & 0xffff0000u);
    a1[2] += __uint_as_float(u1.y << 16);
    a1[3] += __uint_as_float(u1.y & 0xffff0000u);
  }
  float4 c0 = ((const float4*)(b2 + (size_t)mi0[t] * D))[l];
  float4 c1 = ((const float4*)(b2 + (size_t)mi1[t] * D))[l];
  float4 r;
  r.x = w0 * (a0[0] + c0.x) + w1 * (a1[0] + c1.x);
  r.y = w0 * (a0[1] + c0.y) + w1 * (a1[1] + c1.y);
  r.z = w0 * (a0[2] + c0.z) + w1 * (a1[2] + c1.z);
  r.w = w0 * (a0[3] + c0.w) + w1 * (a1[3] + c1.w);
  ((float4*)(out + (size_t)t * D))[l] = r;
}

extern "C" void kernel_launch(void* const* d_in, const int* in_sizes, int n_in,
                              void* d_out, int out_size, void* d_ws, size_t ws_size,
                              hipStream_t stream) {
  const float* x  = (const float*)d_in[0];
  const float* gw = (const float*)d_in[1];
  const float* gb = (const float*)d_in[2];
  const float* w1 = (const float*)d_in[3];
  const float* b1 = (const float*)d_in[4];
  const float* w2 = (const float*)d_in[5];
  const float* b2 = (const float*)d_in[6];
  float* out = (float*)d_out;

  char* ws = (char*)d_ws;
  int*   counts   = (int*)(ws + 0);
  int*   basep    = (int*)(ws + 64);
  int*   rb_n     = (int*)(ws + 128);
  int*   rb_e     = (int*)(ws + 192);                       // 40 ints
  int*   rb_row0  = (int*)(ws + 384);                       // 40 ints
  int*   rb2_n    = (int*)(ws + 576);
  int*   rb2_e    = (int*)(ws + 640);                       // 24 ints
  int*   rb2_row0 = (int*)(ws + 768);                       // 24 ints
  int*   mi0      = (int*)(ws + 1024);
  int*   mi1      = (int*)(ws + 1024 + 1 * 8192);
  int*   mr0      = (int*)(ws + 1024 + 2 * 8192);
  int*   mr1      = (int*)(ws + 1024 + 3 * 8192);
  float* mw0      = (float*)(ws + 1024 + 4 * 8192);
  float* mw1      = (float*)(ws + 1024 + 5 * 8192);
  int*   list_tok = (int*)(ws + 1024 + 6 * 8192);           // 16384 B -> ends 66560
  ushort* xb      = (ushort*)(ws + 66560);                  // 4 MB
  ushort* act_buf = (ushort*)(ws + 4260864);                // 34.6 MB (4224 x 4096 bf16)
  ushort* oe      = (ushort*)(ws + 38863872);               // 17.3 MB (2 x 4224 x 1024 bf16)

  gate_kernel<<<S, 256, 0, stream>>>(x, gw, gb, xb, mi0, mi1, mw0, mw1);
  route_kernel<<<1, 1024, 0, stream>>>(mi0, mi1, counts, basep, list_tok, mr0, mr1,
                                       rb_e, rb_row0, rb_n, rb2_e, rb2_row0, rb2_n);
  gemm1_kernel<<<dim3(64, MAXRB2), 512, 0, stream>>>(xb, w1, b1, counts, basep, list_tok,
                                                     rb2_e, rb2_row0, rb2_n, act_buf);
  gemm2_kernel<<<dim3(8, MAXRB, 2), 256, 0, stream>>>(act_buf, w2, counts, basep,
                                                      rb_e, rb_row0, rb_n, oe);
  combine_kernel<<<S, 256, 0, stream>>>(oe, mr0, mr1, mw0, mw1, mi0, mi1, b2, out);
}

// Round 17
// 282.478 us; speedup vs baseline: 1.5248x; 1.5248x over previous
//
#include <hip/hip_runtime.h>
#include <hip/hip_bf16.h>

#define S 2048
#define D 1024
#define NE 8
#define HF 4096
#define HH 8192
#define BK 32
#define ACT_ROWS 4224  // 4096 + 128 pad
#define MAXRB 40       // 128-row blocks: 4096/128 + 8 - 1 = 39
#define MAXRB2 24      // 256-row blocks: 4096/256 + 8 - 1 = 23

typedef __attribute__((ext_vector_type(8))) __bf16 bf16x8;
typedef __attribute__((ext_vector_type(4))) float f32x4;

__device__ __forceinline__ unsigned cvtpk(float lo, float hi) {
  unsigned r;
  asm("v_cvt_pk_bf16_f32 %0, %1, %2" : "=v"(r) : "v"(lo), "v"(hi));
  return r;  // RNE, lo in low 16
}
__device__ __forceinline__ unsigned bf16b(float f) {
  unsigned b = __float_as_uint(f);
  return (b + 0x7fffu + ((b >> 16) & 1u)) >> 16;  // RNE fp32->bf16 (finite)
}

// ------- gating + x->bf16 fused: one block (256 thr) per token -------
__global__ __launch_bounds__(256) void gate_kernel(
    const float* __restrict__ x, const float* __restrict__ gw,
    const float* __restrict__ gb, ushort* __restrict__ xb,
    int* __restrict__ mi0, int* __restrict__ mi1,
    float* __restrict__ mw0, float* __restrict__ mw1) {
  const int t = blockIdx.x;
  const int l = threadIdx.x;  // handles d = 4l..4l+3
  const float4 xv = ((const float4*)(x + (size_t)t * D))[l];
  uint2 wv = {cvtpk(xv.x, xv.y), cvtpk(xv.z, xv.w)};
  ((uint2*)(xb + (size_t)t * D))[l] = wv;

  float xa[4] = {xv.x, xv.y, xv.z, xv.w};
  float acc[NE];
#pragma unroll
  for (int e = 0; e < NE; ++e) acc[e] = 0.f;
  const float* g0 = gw + (size_t)(4 * l) * NE;
#pragma unroll
  for (int j = 0; j < 4; ++j)
#pragma unroll
    for (int e = 0; e < NE; ++e) acc[e] += xa[j] * g0[j * NE + e];
#pragma unroll
  for (int e = 0; e < NE; ++e) {
    float v = acc[e];
#pragma unroll
    for (int off = 32; off > 0; off >>= 1) v += __shfl_xor(v, off);
    acc[e] = v;
  }
  __shared__ float sm[4][NE];
  const int wid = l >> 6;
  if ((l & 63) == 0) {
#pragma unroll
    for (int e = 0; e < NE; ++e) sm[wid][e] = acc[e];
  }
  __syncthreads();
  if (l == 0) {
    float lg[NE];
#pragma unroll
    for (int e = 0; e < NE; ++e)
      lg[e] = sm[0][e] + sm[1][e] + sm[2][e] + sm[3][e] + gb[e];
    int i0 = 0; float m0 = lg[0];
#pragma unroll
    for (int e = 1; e < NE; ++e) if (lg[e] > m0) { m0 = lg[e]; i0 = e; }  // strict >: jax tie-break
    int i1 = -1; float m1 = -3.4e38f;
#pragma unroll
    for (int e = 0; e < NE; ++e) if (e != i0 && lg[e] > m1) { m1 = lg[e]; i1 = e; }
    float p = __expf(m1 - m0);
    float inv = 1.f / (1.f + p);
    mi0[t] = i0; mi1[t] = i1;
    mw0[t] = inv; mw1[t] = p * inv;
  }
}

// --- routing: counts + prefix + slots + compact rowblock tables (128 & 256 gran) ---
__global__ __launch_bounds__(1024) void route_kernel(
    const int* __restrict__ mi0, const int* __restrict__ mi1,
    int* __restrict__ counts, int* __restrict__ basep, int* __restrict__ list_tok,
    int* __restrict__ mr0, int* __restrict__ mr1,
    int* __restrict__ rb_e, int* __restrict__ rb_row0, int* __restrict__ rb_n,
    int* __restrict__ rb2_e, int* __restrict__ rb2_row0, int* __restrict__ rb2_n) {
  __shared__ int cnt[NE];
  __shared__ int cur[NE];
  const int t = threadIdx.x;
  if (t < NE) cnt[t] = 0;
  __syncthreads();
  const int e0a = mi0[t], e1a = mi1[t];
  const int e0b = mi0[t + 1024], e1b = mi1[t + 1024];
  atomicAdd(&cnt[e0a], 1); atomicAdd(&cnt[e1a], 1);
  atomicAdd(&cnt[e0b], 1); atomicAdd(&cnt[e1b], 1);
  __syncthreads();
  if (t == 0) {
    int s = 0;
#pragma unroll
    for (int e = 0; e < NE; ++e) { basep[e] = s; cur[e] = s; s += cnt[e]; }
    basep[NE] = s;
    int nrb = 0, nrb2 = 0;
    for (int e = 0; e < NE; ++e) {
      for (int r0 = 0; r0 < cnt[e]; r0 += 128) {
        rb_e[nrb] = e; rb_row0[nrb] = r0; ++nrb;
      }
      for (int r0 = 0; r0 < cnt[e]; r0 += 256) {
        rb2_e[nrb2] = e; rb2_row0[nrb2] = r0; ++nrb2;
      }
    }
    *rb_n = nrb;    // <= 39
    *rb2_n = nrb2;  // <= 23
  }
  if (t < NE) counts[t] = cnt[t];
  __syncthreads();
  int r;
  r = atomicAdd(&cur[e0a], 1); list_tok[r] = t; mr0[t] = r;
  r = atomicAdd(&cur[e1a], 1); list_tok[r] = t; mr1[t] = r;
  r = atomicAdd(&cur[e0b], 1); list_tok[r] = t + 1024; mr0[t + 1024] = r;
  r = atomicAdd(&cur[e1b], 1); list_tok[r] = t + 1024; mr1[t + 1024] = r;
}

// ---- GEMM1 + SwiGLU, BM=256, 8 waves, fp32-W direct, ALL-REGISTER staging ----
// No global_load_lds anywhere -> __syncthreads needs only lgkmcnt (no vmcnt(0)
// drain of in-flight global loads).  2-deep prefetch: loads for tile it+2 are
// issued at step it (two named register sets, loop unrolled x2 per rule #20).
#define G1_STEP(LA0, LA1, LB0, LB1, WA0, WA1, WB0, WB1, CUR, IT)               \
  {                                                                            \
    if ((IT) + 2 < D / BK) {  /* issue loads for tile IT+2 */                  \
      const size_t koff = (size_t)((IT) + 2) * BK;                             \
      LB0 = *(const float4*)(pB + koff * HH);                                  \
      LB1 = *(const float4*)(pB + koff * HH + HH);                             \
      LA0 = *(const uint4*)(pa0 + koff);                                       \
      LA1 = *(const uint4*)(pa1 + koff);                                       \
    }                                                                          \
    bf16x8 af[4], bfr[2][2];                                                   \
    _Pragma("unroll")                                                          \
    for (int mi = 0; mi < 4; ++mi)                                             \
      af[mi] = *(const bf16x8*)&As[CUR][wm + mi * 16 + lr][kg * 8];            \
    _Pragma("unroll")                                                          \
    for (int h = 0; h < 2; ++h)                                                \
      _Pragma("unroll")                                                        \
      for (int ni = 0; ni < 2; ++ni) {                                         \
        const int col = wn + ni * 16 + lr;                                     \
        uint4 tv;                                                              \
        tv.x = Bs[CUR][h * 16 + kg * 4 + 0][col];                              \
        tv.y = Bs[CUR][h * 16 + kg * 4 + 1][col];                              \
        tv.z = Bs[CUR][h * 16 + kg * 4 + 2][col];                              \
        tv.w = Bs[CUR][h * 16 + kg * 4 + 3][col];                              \
        bfr[h][ni] = *(const bf16x8*)&tv;                                      \
      }                                                                        \
    _Pragma("unroll")                                                          \
    for (int h = 0; h < 2; ++h)                                                \
      _Pragma("unroll")                                                        \
      for (int mi = 0; mi < 4; ++mi)                                           \
        _Pragma("unroll")                                                      \
        for (int ni = 0; ni < 2; ++ni)                                         \
          acc[h][mi][ni] = __builtin_amdgcn_mfma_f32_16x16x32_bf16(            \
              af[mi], bfr[h][ni], acc[h][mi][ni], 0, 0, 0);                    \
    if ((IT) + 1 < D / BK) {  /* write tile IT+1 (loaded 2 steps ago) */       \
      uint4 u = {cvtpk(WB0.x, WB1.x), cvtpk(WB0.y, WB1.y),                     \
                 cvtpk(WB0.z, WB1.z), cvtpk(WB0.w, WB1.w)};                    \
      *(uint4*)&Bs[(CUR) ^ 1][half * 16 + kp][n4] = u;                         \
      *(uint4*)&As[(CUR) ^ 1][arow0][ac] = WA0;                                \
      *(uint4*)&As[(CUR) ^ 1][arow0 + 16][ac] = WA1;                           \
    }                                                                          \
    __syncthreads();                                                           \
  }

__global__ __launch_bounds__(512) void gemm1_kernel(
    const ushort* __restrict__ xb, const float* __restrict__ w1,
    const float* __restrict__ b1, const int* __restrict__ counts,
    const int* __restrict__ basep, const int* __restrict__ list_tok,
    const int* __restrict__ rb2_e, const int* __restrict__ rb2_row0,
    const int* __restrict__ rb2_n, ushort* __restrict__ act_buf) {
  const int rb = blockIdx.y;
  if (rb >= *rb2_n) return;
  const int e = rb2_e[rb];
  const int row0 = rb2_row0[rb];
  const int cnt = counts[e];
  const int jt = blockIdx.x * 64;
  const float* __restrict__ Wf = w1 + (size_t)e * D * HH;  // [k=1024][n=8192] fp32
  const int gbase = basep[e];

  __shared__ ushort As[2][256][BK];   // 32 KB
  __shared__ unsigned Bs[2][32][68];  // 17.4 KB

  const int tid = threadIdx.x;
  const int w = tid >> 6;   // 0..7
  const int i = tid & 63;
  const int lr = i & 15;
  const int kg = i >> 4;
  const int wm = (w >> 1) * 64;
  const int wn = (w & 1) * 32;

  // A: same coalesced gather addresses as the gll16 version; explicit ds_write
  const int arow0 = w * 32 + (i >> 2);
  const int ac = (i & 3) * 8;
  int s0 = row0 + arow0; if (s0 >= cnt) s0 = cnt - 1;
  int s1 = row0 + arow0 + 16; if (s1 >= cnt) s1 = cnt - 1;
  const ushort* pa0 = xb + (size_t)list_tok[gbase + s0] * D + ac;
  const ushort* pa1 = xb + (size_t)list_tok[gbase + s1] * D + ac;

  // B staging: thread = (half, kpair kp, n4..n4+3); 2 coalesced float4 loads
  const int half = tid >> 8;
  const int kp = (tid >> 4) & 15;
  const int n4 = (tid & 15) * 4;
  const float* pB = Wf + (size_t)(2 * kp) * HH + jt + n4 + half * HF;

  f32x4 acc[2][4][2] = {};  // [half][mi][ni]
  uint4 aA0, aA1, aB0, aB1;
  float4 bA0, bA1, bB0, bB1;

  // prologue: tile0 -> LDS[0]; tile1 -> register set B
  bA0 = *(const float4*)(pB);
  bA1 = *(const float4*)(pB + HH);
  aA0 = *(const uint4*)(pa0);
  aA1 = *(const uint4*)(pa1);
  {
    uint4 u = {cvtpk(bA0.x, bA1.x), cvtpk(bA0.y, bA1.y),
               cvtpk(bA0.z, bA1.z), cvtpk(bA0.w, bA1.w)};
    *(uint4*)&Bs[0][half * 16 + kp][n4] = u;
    *(uint4*)&As[0][arow0][ac] = aA0;
    *(uint4*)&As[0][arow0 + 16][ac] = aA1;
  }
  bB0 = *(const float4*)(pB + (size_t)BK * HH);
  bB1 = *(const float4*)(pB + (size_t)BK * HH + HH);
  aB0 = *(const uint4*)(pa0 + BK);
  aB1 = *(const uint4*)(pa1 + BK);
  __syncthreads();

#pragma unroll 1
  for (int it = 0; it < D / BK; it += 2) {
    G1_STEP(aA0, aA1, bA0, bA1, aB0, aB1, bB0, bB1, 0, it);
    G1_STEP(aB0, aB1, bB0, bB1, aA0, aA1, bA0, bA1, 1, it + 1);
  }

#pragma unroll
  for (int mi = 0; mi < 4; ++mi)
#pragma unroll
    for (int ni = 0; ni < 2; ++ni) {
      const int c = jt + wn + ni * 16 + lr;
      const float bx = b1[(size_t)e * HH + c];
      const float bg = b1[(size_t)e * HH + HF + c];
      f32x4 vx = acc[0][mi][ni];
      f32x4 vg = acc[1][mi][ni];
#pragma unroll
      for (int q = 0; q < 4; ++q) {
        const int slot = row0 + wm + mi * 16 + kg * 4 + q;
        if (slot < cnt) {
          float xv = vx[q] + bx;
          float g = vg[q] + bg;
          float a = g / (1.f + __expf(-g)) * xv;
          act_buf[(size_t)(gbase + slot) * HF + c] = (ushort)bf16b(a);
        }
      }
    }
}

// ---- GEMM2 (K-split 2), fp32-W2 direct, all-register staging, 2-deep ----
#define G2_STEP(LA0, LA1, LB0, LB1, LB2, LB3, WA0, WA1, WB0, WB1, WB2, WB3, CUR, IT) \
  {                                                                            \
    if ((IT) + 2 < (HF / 2) / BK) {                                            \
      const size_t koff = (size_t)((IT) + 2) * BK;                             \
      LB0 = *(const float4*)(pB0 + koff * D);                                  \
      LB1 = *(const float4*)(pB0 + koff * D + D);                              \
      LB2 = *(const float4*)(pB1 + koff * D);                                  \
      LB3 = *(const float4*)(pB1 + koff * D + D);                              \
      LA0 = *(const uint4*)(pa0 + koff);                                       \
      LA1 = *(const uint4*)(pa1 + koff);                                       \
    }                                                                          \
    bf16x8 af[4], bfr[4];                                                      \
    _Pragma("unroll")                                                          \
    for (int mi = 0; mi < 4; ++mi)                                             \
      af[mi] = *(const bf16x8*)&As[CUR][wm + mi * 16 + lr][kg * 8];            \
    _Pragma("unroll")                                                          \
    for (int ni = 0; ni < 4; ++ni) {                                           \
      const int col = wn + ni * 16 + lr;                                       \
      uint4 tv;                                                                \
      tv.x = Bs[CUR][kg * 4 + 0][col];                                         \
      tv.y = Bs[CUR][kg * 4 + 1][col];                                         \
      tv.z = Bs[CUR][kg * 4 + 2][col];                                         \
      tv.w = Bs[CUR][kg * 4 + 3][col];                                         \
      bfr[ni] = *(const bf16x8*)&tv;                                           \
    }                                                                          \
    _Pragma("unroll")                                                          \
    for (int mi = 0; mi < 4; ++mi)                                             \
      _Pragma("unroll")                                                        \
      for (int ni = 0; ni < 4; ++ni)                                           \
        acc[mi][ni] = __builtin_amdgcn_mfma_f32_16x16x32_bf16(                 \
            af[mi], bfr[ni], acc[mi][ni], 0, 0, 0);                            \
    if ((IT) + 1 < (HF / 2) / BK) {                                            \
      uint4 u0 = {cvtpk(WB0.x, WB1.x), cvtpk(WB0.y, WB1.y),                    \
                  cvtpk(WB0.z, WB1.z), cvtpk(WB0.w, WB1.w)};                   \
      uint4 u1 = {cvtpk(WB2.x, WB3.x), cvtpk(WB2.y, WB3.y),                    \
                  cvtpk(WB2.z, WB3.z), cvtpk(WB2.w, WB3.w)};                   \
      *(uint4*)&Bs[(CUR) ^ 1][grp][n4] = u0;                                   \
      *(uint4*)&Bs[(CUR) ^ 1][8 + grp][n4] = u1;                               \
      *(uint4*)&As[(CUR) ^ 1][arow0][ac] = WA0;                                \
      *(uint4*)&As[(CUR) ^ 1][arow0 + 16][ac] = WA1;                           \
    }                                                                          \
    __syncthreads();                                                           \
  }

__global__ __launch_bounds__(256) void gemm2_kernel(
    const ushort* __restrict__ act_buf, const float* __restrict__ w2,
    const int* __restrict__ counts, const int* __restrict__ basep,
    const int* __restrict__ rb_e, const int* __restrict__ rb_row0,
    const int* __restrict__ rb_n, ushort* __restrict__ oe) {
  const int rb = blockIdx.y;
  if (rb >= *rb_n) return;
  const int e = rb_e[rb];
  const int row0 = rb_row0[rb];
  const int cnt = counts[e];
  const int split = blockIdx.z;
  const int jt = blockIdx.x * 128;
  const float* __restrict__ Wf = w2 + (size_t)e * HF * D;  // [kf=4096][n=1024] fp32
  const int gbase = basep[e];
  const size_t kbase = (size_t)split * (HF / 2);

  __shared__ ushort As[2][128][BK];    // 16 KB
  __shared__ unsigned Bs[2][16][132];  // 16.9 KB

  const int tid = threadIdx.x;
  const int w = tid >> 6;
  const int i = tid & 63;
  const int lr = i & 15;
  const int kg = i >> 4;
  const int wm = (w >> 1) * 64;
  const int wn = (w & 1) * 64;

  const int arow0 = w * 32 + (i >> 2);
  const int ac = (i & 3) * 8;
  const ushort* pa0 = act_buf + (size_t)(gbase + row0 + arow0) * HF + kbase + ac;
  const ushort* pa1 = pa0 + (size_t)16 * HF;

  const int grp = tid >> 5;          // 0..7
  const int n4 = (tid & 31) * 4;     // 0..124
  const float* pB0 = Wf + (kbase + 2 * grp) * D + jt + n4;
  const float* pB1 = pB0 + (size_t)16 * D;

  f32x4 acc[4][4] = {};
  uint4 aA0, aA1, aB0, aB1;
  float4 bA0, bA1, bA2, bA3, bB0, bB1, bB2, bB3;

  // prologue: tile0 -> LDS[0]; tile1 -> register set B
  bA0 = *(const float4*)(pB0);
  bA1 = *(const float4*)(pB0 + D);
  bA2 = *(const float4*)(pB1);
  bA3 = *(const float4*)(pB1 + D);
  aA0 = *(const uint4*)(pa0);
  aA1 = *(const uint4*)(pa1);
  {
    uint4 u0 = {cvtpk(bA0.x, bA1.x), cvtpk(bA0.y, bA1.y),
                cvtpk(bA0.z, bA1.z), cvtpk(bA0.w, bA1.w)};
    uint4 u1 = {cvtpk(bA2.x, bA3.x), cvtpk(bA2.y, bA3.y),
                cvtpk(bA2.z, bA3.z), cvtpk(bA2.w, bA3.w)};
    *(uint4*)&Bs[0][grp][n4] = u0;
    *(uint4*)&Bs[0][8 + grp][n4] = u1;
    *(uint4*)&As[0][arow0][ac] = aA0;
    *(uint4*)&As[0][arow0 + 16][ac] = aA1;
  }
  bB0 = *(const float4*)(pB0 + (size_t)BK * D);
  bB1 = *(const float4*)(pB0 + (size_t)BK * D + D);
  bB2 = *(const float4*)(pB1 + (size_t)BK * D);
  bB3 = *(const float4*)(pB1 + (size_t)BK * D + D);
  aB0 = *(const uint4*)(pa0 + BK);
  aB1 = *(const uint4*)(pa1 + BK);
  __syncthreads();

#pragma unroll 1
  for (int it = 0; it < (HF / 2) / BK; it += 2) {
    G2_STEP(aA0, aA1, bA0, bA1, bA2, bA3, aB0, aB1, bB0, bB1, bB2, bB3, 0, it);
    G2_STEP(aB0, aB1, bB0, bB1, bB2, bB3, aA0, aA1, bA0, bA1, bA2, bA3, 1, it + 1);
  }

#pragma unroll
  for (int mi = 0; mi < 4; ++mi)
#pragma unroll
    for (int ni = 0; ni < 4; ++ni) {
      f32x4 v = acc[mi][ni];
#pragma unroll
      for (int q = 0; q < 4; ++q) {
        const int slot = row0 + wm + mi * 16 + kg * 4 + q;
        if (slot < cnt)
          oe[((size_t)split * ACT_ROWS + gbase + slot) * D + jt + wn + ni * 16 + lr] =
              (ushort)bf16b(v[q]);
      }
    }
}

// ---- combine: out[t] = w0*(sum_s oe[s][r0] + b2[e0]) + w1*(sum_s oe[s][r1] + b2[e1]) ----
__global__ void combine_kernel(const ushort* __restrict__ oe,
                               const int* __restrict__ mr0, const int* __restrict__ mr1,
                               const float* __restrict__ mw0, const float* __restrict__ mw1,
                               const int* __restrict__ mi0, const int* __restrict__ mi1,
                               const float* __restrict__ b2, float* __restrict__ out) {
  const int t = blockIdx.x;
  const int l = threadIdx.x;  // 4 elems per thread
  const float w0 = mw0[t], w1 = mw1[t];
  const int r0 = mr0[t], r1 = mr1[t];
  float a0[4] = {0.f, 0.f, 0.f, 0.f}, a1[4] = {0.f, 0.f, 0.f, 0.f};
#pragma unroll
  for (int s = 0; s < 2; ++s) {
    uint2 u0 = *(const uint2*)(oe + ((size_t)s * ACT_ROWS + r0) * D + l * 4);
    uint2 u1 = *(const uint2*)(oe + ((size_t)s * ACT_ROWS + r1) * D + l * 4);
    a0[0] += __uint_as_float(u0.x << 16);
    a0[1] += __uint_as_float(u0.x & 0xffff0000u);
    a0[2] += __uint_as_float(u0.y << 16);
    a0[3] += __uint_as_float(u0.y & 0xffff0000u);
    a1[0] += __uint_as_float(u1.x << 16);
    a1[1] += __uint_as_float(u1.x & 0xffff0000u);
    a1[2] += __uint_as_float(u1.y << 16);
    a1[3] += __uint_as_float(u1.y & 0xffff0000u);
  }
  float4 c0 = ((const float4*)(b2 + (size_t)mi0[t] * D))[l];
  float4 c1 = ((const float4*)(b2 + (size_t)mi1[t] * D))[l];
  float4 r;
  r.x = w0 * (a0[0] + c0.x) + w1 * (a1[0] + c1.x);
  r.y = w0 * (a0[1] + c0.y) + w1 * (a1[1] + c1.y);
  r.z = w0 * (a0[2] + c0.z) + w1 * (a1[2] + c1.z);
  r.w = w0 * (a0[3] + c0.w) + w1 * (a1[3] + c1.w);
  ((float4*)(out + (size_t)t * D))[l] = r;
}

extern "C" void kernel_launch(void* const* d_in, const int* in_sizes, int n_in,
                              void* d_out, int out_size, void* d_ws, size_t ws_size,
                              hipStream_t stream) {
  const float* x  = (const float*)d_in[0];
  const float* gw = (const float*)d_in[1];
  const float* gb = (const float*)d_in[2];
  const float* w1 = (const float*)d_in[3];
  const float* b1 = (const float*)d_in[4];
  const float* w2 = (const float*)d_in[5];
  const float* b2 = (const float*)d_in[6];
  float* out = (float*)d_out;

  char* ws = (char*)d_ws;
  int*   counts   = (int*)(ws + 0);
  int*   basep    = (int*)(ws + 64);
  int*   rb_n     = (int*)(ws + 128);
  int*   rb_e     = (int*)(ws + 192);                       // 40 ints
  int*   rb_row0  = (int*)(ws + 384);                       // 40 ints
  int*   rb2_n    = (int*)(ws + 576);
  int*   rb2_e    = (int*)(ws + 640);                       // 24 ints
  int*   rb2_row0 = (int*)(ws + 768);                       // 24 ints
  int*   mi0      = (int*)(ws + 1024);
  int*   mi1      = (int*)(ws + 1024 + 1 * 8192);
  int*   mr0      = (int*)(ws + 1024 + 2 * 8192);
  int*   mr1      = (int*)(ws + 1024 + 3 * 8192);
  float* mw0      = (float*)(ws + 1024 + 4 * 8192);
  float* mw1      = (float*)(ws + 1024 + 5 * 8192);
  int*   list_tok = (int*)(ws + 1024 + 6 * 8192);           // 16384 B -> ends 66560
  ushort* xb      = (ushort*)(ws + 66560);                  // 4 MB
  ushort* act_buf = (ushort*)(ws + 4260864);                // 34.6 MB (4224 x 4096 bf16)
  ushort* oe      = (ushort*)(ws + 38863872);               // 17.3 MB (2 x 4224 x 1024 bf16)

  gate_kernel<<<S, 256, 0, stream>>>(x, gw, gb, xb, mi0, mi1, mw0, mw1);
  route_kernel<<<1, 1024, 0, stream>>>(mi0, mi1, counts, basep, list_tok, mr0, mr1,
                                       rb_e, rb_row0, rb_n, rb2_e, rb2_row0, rb2_n);
  gemm1_kernel<<<dim3(64, MAXRB2), 512, 0, stream>>>(xb, w1, b1, counts, basep, list_tok,
                                                     rb2_e, rb2_row0, rb2_n, act_buf);
  gemm2_kernel<<<dim3(8, MAXRB, 2), 256, 0, stream>>>(act_buf, w2, counts, basep,
                                                      rb_e, rb_row0, rb_n, oe);
  combine_kernel<<<S, 256, 0, stream>>>(oe, mr0, mr1, mw0, mw1, mi0, mi1, b2, out);
}

// Round 18
// 267.124 us; speedup vs baseline: 1.6125x; 1.0575x over previous
//
#include <hip/hip_runtime.h>
#include <hip/hip_bf16.h>

#define S 2048
#define D 1024
#define NE 8
#define HF 4096
#define HH 8192
#define BK 32
#define ACT_ROWS 4224  // 4096 + 128 pad
#define MAXRB 40       // 128-row blocks: 4096/128 + 8 - 1 = 39
#define MAXRB2 24      // 256-row blocks: 4096/256 + 8 - 1 = 23
#define NSPLIT 4

typedef __attribute__((ext_vector_type(8))) __bf16 bf16x8;
typedef __attribute__((ext_vector_type(4))) float f32x4;

__device__ __forceinline__ unsigned cvtpk(float lo, float hi) {
  unsigned r;
  asm("v_cvt_pk_bf16_f32 %0, %1, %2" : "=v"(r) : "v"(lo), "v"(hi));
  return r;  // RNE, lo in low 16
}
__device__ __forceinline__ unsigned bf16b(float f) {
  unsigned b = __float_as_uint(f);
  return (b + 0x7fffu + ((b >> 16) & 1u)) >> 16;  // RNE fp32->bf16 (finite)
}
__device__ __forceinline__ void gll16(const ushort* g, ushort* l) {
  __builtin_amdgcn_global_load_lds(
      (const __attribute__((address_space(1))) void*)g,
      (__attribute__((address_space(3))) void*)l, 16, 0, 0);
}

// ------- gating + x->bf16 fused: one block (256 thr) per token -------
__global__ __launch_bounds__(256) void gate_kernel(
    const float* __restrict__ x, const float* __restrict__ gw,
    const float* __restrict__ gb, ushort* __restrict__ xb,
    int* __restrict__ mi0, int* __restrict__ mi1,
    float* __restrict__ mw0, float* __restrict__ mw1) {
  const int t = blockIdx.x;
  const int l = threadIdx.x;  // handles d = 4l..4l+3
  const float4 xv = ((const float4*)(x + (size_t)t * D))[l];
  uint2 wv = {cvtpk(xv.x, xv.y), cvtpk(xv.z, xv.w)};
  ((uint2*)(xb + (size_t)t * D))[l] = wv;

  float xa[4] = {xv.x, xv.y, xv.z, xv.w};
  float acc[NE];
#pragma unroll
  for (int e = 0; e < NE; ++e) acc[e] = 0.f;
  const float* g0 = gw + (size_t)(4 * l) * NE;
#pragma unroll
  for (int j = 0; j < 4; ++j)
#pragma unroll
    for (int e = 0; e < NE; ++e) acc[e] += xa[j] * g0[j * NE + e];
#pragma unroll
  for (int e = 0; e < NE; ++e) {
    float v = acc[e];
#pragma unroll
    for (int off = 32; off > 0; off >>= 1) v += __shfl_xor(v, off);
    acc[e] = v;
  }
  __shared__ float sm[4][NE];
  const int wid = l >> 6;
  if ((l & 63) == 0) {
#pragma unroll
    for (int e = 0; e < NE; ++e) sm[wid][e] = acc[e];
  }
  __syncthreads();
  if (l == 0) {
    float lg[NE];
#pragma unroll
    for (int e = 0; e < NE; ++e)
      lg[e] = sm[0][e] + sm[1][e] + sm[2][e] + sm[3][e] + gb[e];
    int i0 = 0; float m0 = lg[0];
#pragma unroll
    for (int e = 1; e < NE; ++e) if (lg[e] > m0) { m0 = lg[e]; i0 = e; }  // strict >: jax tie-break
    int i1 = -1; float m1 = -3.4e38f;
#pragma unroll
    for (int e = 0; e < NE; ++e) if (e != i0 && lg[e] > m1) { m1 = lg[e]; i1 = e; }
    float p = __expf(m1 - m0);
    float inv = 1.f / (1.f + p);
    mi0[t] = i0; mi1[t] = i1;
    mw0[t] = inv; mw1[t] = p * inv;
  }
}

// --- routing: counts + prefix + slots + compact rowblock tables (128 & 256 gran) ---
__global__ __launch_bounds__(1024) void route_kernel(
    const int* __restrict__ mi0, const int* __restrict__ mi1,
    int* __restrict__ counts, int* __restrict__ basep, int* __restrict__ list_tok,
    int* __restrict__ mr0, int* __restrict__ mr1,
    int* __restrict__ rb_e, int* __restrict__ rb_row0, int* __restrict__ rb_n,
    int* __restrict__ rb2_e, int* __restrict__ rb2_row0, int* __restrict__ rb2_n) {
  __shared__ int cnt[NE];
  __shared__ int cur[NE];
  const int t = threadIdx.x;
  if (t < NE) cnt[t] = 0;
  __syncthreads();
  const int e0a = mi0[t], e1a = mi1[t];
  const int e0b = mi0[t + 1024], e1b = mi1[t + 1024];
  atomicAdd(&cnt[e0a], 1); atomicAdd(&cnt[e1a], 1);
  atomicAdd(&cnt[e0b], 1); atomicAdd(&cnt[e1b], 1);
  __syncthreads();
  if (t == 0) {
    int s = 0;
#pragma unroll
    for (int e = 0; e < NE; ++e) { basep[e] = s; cur[e] = s; s += cnt[e]; }
    basep[NE] = s;
    int nrb = 0, nrb2 = 0;
    for (int e = 0; e < NE; ++e) {
      for (int r0 = 0; r0 < cnt[e]; r0 += 128) {
        rb_e[nrb] = e; rb_row0[nrb] = r0; ++nrb;
      }
      for (int r0 = 0; r0 < cnt[e]; r0 += 256) {
        rb2_e[nrb2] = e; rb2_row0[nrb2] = r0; ++nrb2;
      }
    }
    *rb_n = nrb;    // <= 39
    *rb2_n = nrb2;  // <= 23
  }
  if (t < NE) counts[t] = cnt[t];
  __syncthreads();
  int r;
  r = atomicAdd(&cur[e0a], 1); list_tok[r] = t; mr0[t] = r;
  r = atomicAdd(&cur[e1a], 1); list_tok[r] = t; mr1[t] = r;
  r = atomicAdd(&cur[e0b], 1); list_tok[r] = t + 1024; mr0[t + 1024] = r;
  r = atomicAdd(&cur[e1b], 1); list_tok[r] = t + 1024; mr1[t + 1024] = r;
}

// ---- GEMM1 + SwiGLU, BM=256, 8 waves: A via gll16, B fp32-direct via reg+LDS ----
__global__ __launch_bounds__(512) void gemm1_kernel(
    const ushort* __restrict__ xb, const float* __restrict__ w1,
    const float* __restrict__ b1, const int* __restrict__ counts,
    const int* __restrict__ basep, const int* __restrict__ list_tok,
    const int* __restrict__ rb2_e, const int* __restrict__ rb2_row0,
    const int* __restrict__ rb2_n, ushort* __restrict__ act_buf) {
  const int rb = blockIdx.y;
  if (rb >= *rb2_n) return;
  const int e = rb2_e[rb];
  const int row0 = rb2_row0[rb];
  const int cnt = counts[e];
  const int jt = blockIdx.x * 64;
  const float* __restrict__ Wf = w1 + (size_t)e * D * HH;  // [k=1024][n=8192] fp32
  const int gbase = basep[e];

  __shared__ ushort As[2][256][BK];   // 32 KB
  __shared__ unsigned Bs[2][32][68];  // 17.4 KB ([half*16+kp][n 0..63, +4 pad])

  const int tid = threadIdx.x;
  const int w = tid >> 6;   // 0..7
  const int i = tid & 63;

  // A staging: wave w stages rows w*32 .. w*32+31 (2x gll16)
  const int rA0 = w * 32 + (i >> 2);
  const int rA1 = rA0 + 16;
  int s0 = row0 + rA0; if (s0 >= cnt) s0 = cnt - 1;
  int s1 = row0 + rA1; if (s1 >= cnt) s1 = cnt - 1;
  const ushort* pa0 = xb + (size_t)list_tok[gbase + s0] * D + (i & 3) * 8;
  const ushort* pa1 = xb + (size_t)list_tok[gbase + s1] * D + (i & 3) * 8;

  // B staging: thread = (half, kpair kp, n4..n4+3); 2 coalesced float4 loads
  const int half = tid >> 8;        // 0: x-half, 1: gate-half
  const int kp = (tid >> 4) & 15;   // 0..15
  const int n4 = (tid & 15) * 4;    // 0..60
  const float* pB = Wf + (size_t)(2 * kp) * HH + jt + n4 + half * HF;

  const int wm = (w >> 1) * 64;     // 0,64,128,192
  const int wn = (w & 1) * 32;
  const int lr = i & 15;
  const int kg = i >> 4;            // 0..3

  f32x4 acc[2][4][2] = {};  // [half][mi][ni]

  // prologue: tile 0
  {
    float4 b0v = *(const float4*)(pB);
    float4 b1v = *(const float4*)(pB + HH);
    uint4 u = {cvtpk(b0v.x, b1v.x), cvtpk(b0v.y, b1v.y),
               cvtpk(b0v.z, b1v.z), cvtpk(b0v.w, b1v.w)};
    *(uint4*)&Bs[0][half * 16 + kp][n4] = u;
  }
  gll16(pa0, &As[0][w * 32][0]);
  gll16(pa1, &As[0][w * 32 + 16][0]);
  __syncthreads();

  int cur = 0;
#pragma unroll 1
  for (int it = 0; it < D / BK; ++it) {
    const bool pf = (it + 1 < D / BK);
    float4 b0v, b1v;
    if (pf) {  // issue-early: next-tile loads ride under the MFMA block
      const size_t koff = (size_t)(it + 1) * BK * HH;
      b0v = *(const float4*)(pB + koff);
      b1v = *(const float4*)(pB + koff + HH);
      const int ko = (it + 1) * BK;
      gll16(pa0 + ko, &As[cur ^ 1][w * 32][0]);
      gll16(pa1 + ko, &As[cur ^ 1][w * 32 + 16][0]);
    }
    bf16x8 af[4], bfr[2][2];
#pragma unroll
    for (int mi = 0; mi < 4; ++mi)
      af[mi] = *(const bf16x8*)&As[cur][wm + mi * 16 + lr][kg * 8];
#pragma unroll
    for (int h = 0; h < 2; ++h)
#pragma unroll
      for (int ni = 0; ni < 2; ++ni) {
        const int col = wn + ni * 16 + lr;
        uint4 tv;
        tv.x = Bs[cur][h * 16 + kg * 4 + 0][col];
        tv.y = Bs[cur][h * 16 + kg * 4 + 1][col];
        tv.z = Bs[cur][h * 16 + kg * 4 + 2][col];
        tv.w = Bs[cur][h * 16 + kg * 4 + 3][col];
        bfr[h][ni] = *(const bf16x8*)&tv;
      }
#pragma unroll
    for (int h = 0; h < 2; ++h)
#pragma unroll
      for (int mi = 0; mi < 4; ++mi)
#pragma unroll
        for (int ni = 0; ni < 2; ++ni)
          acc[h][mi][ni] = __builtin_amdgcn_mfma_f32_16x16x32_bf16(af[mi], bfr[h][ni],
                                                                   acc[h][mi][ni], 0, 0, 0);
    if (pf) {  // write-late into the freed buffer
      uint4 u = {cvtpk(b0v.x, b1v.x), cvtpk(b0v.y, b1v.y),
                 cvtpk(b0v.z, b1v.z), cvtpk(b0v.w, b1v.w)};
      *(uint4*)&Bs[cur ^ 1][half * 16 + kp][n4] = u;
    }
    __syncthreads();
    cur ^= 1;
  }

#pragma unroll
  for (int mi = 0; mi < 4; ++mi)
#pragma unroll
    for (int ni = 0; ni < 2; ++ni) {
      const int c = jt + wn + ni * 16 + lr;
      const float bx = b1[(size_t)e * HH + c];
      const float bg = b1[(size_t)e * HH + HF + c];
      f32x4 vx = acc[0][mi][ni];
      f32x4 vg = acc[1][mi][ni];
#pragma unroll
      for (int q = 0; q < 4; ++q) {
        const int slot = row0 + wm + mi * 16 + kg * 4 + q;
        if (slot < cnt) {
          float xv = vx[q] + bx;
          float g = vg[q] + bg;
          float a = g / (1.f + __expf(-g)) * xv;
          act_buf[(size_t)(gbase + slot) * HF + c] = (ushort)bf16b(a);
        }
      }
    }
}

// ---- GEMM2 (K-split 4): A via gll16, B fp32-direct; bf16 oe stores ----
// split 4 (was 2): 1152 vs 576 active blocks -> tail quantization 33% -> 11%.
__global__ __launch_bounds__(256) void gemm2_kernel(
    const ushort* __restrict__ act_buf, const float* __restrict__ w2,
    const int* __restrict__ counts, const int* __restrict__ basep,
    const int* __restrict__ rb_e, const int* __restrict__ rb_row0,
    const int* __restrict__ rb_n, ushort* __restrict__ oe) {
  const int rb = blockIdx.y;
  if (rb >= *rb_n) return;
  const int e = rb_e[rb];
  const int row0 = rb_row0[rb];
  const int cnt = counts[e];
  const int split = blockIdx.z;
  const int jt = blockIdx.x * 128;
  const float* __restrict__ Wf = w2 + (size_t)e * HF * D;  // [kf=4096][n=1024] fp32
  const int gbase = basep[e];
  const size_t kbase = (size_t)split * (HF / NSPLIT);

  __shared__ ushort As[2][128][BK];
  __shared__ unsigned Bs[2][16][132];  // [kp][n 0..127, +4 pad]

  const int tid = threadIdx.x;
  const int w = tid >> 6;
  const int i = tid & 63;

  const int rA0 = w * 32 + (i >> 2);
  const ushort* pa0 = act_buf + (size_t)(gbase + row0 + rA0) * HF + kbase + (i & 3) * 8;
  const ushort* pa1 = pa0 + (size_t)16 * HF;

  // B staging: thread = (kpairs grp & grp+8, n4..n4+3)
  const int grp = tid >> 5;          // 0..7
  const int n4 = (tid & 31) * 4;     // 0..124
  const float* pB0 = Wf + (kbase + 2 * grp) * D + jt + n4;       // kp = grp
  const float* pB1 = pB0 + (size_t)16 * D;                        // kp = grp + 8

  const int wm = (w >> 1) * 64;
  const int wn = (w & 1) * 64;
  const int lr = i & 15;
  const int kg = i >> 4;

  f32x4 acc[4][4] = {};

  {
    float4 a0 = *(const float4*)(pB0);
    float4 a1 = *(const float4*)(pB0 + D);
    float4 c0 = *(const float4*)(pB1);
    float4 c1 = *(const float4*)(pB1 + D);
    uint4 u0 = {cvtpk(a0.x, a1.x), cvtpk(a0.y, a1.y), cvtpk(a0.z, a1.z), cvtpk(a0.w, a1.w)};
    uint4 u1 = {cvtpk(c0.x, c1.x), cvtpk(c0.y, c1.y), cvtpk(c0.z, c1.z), cvtpk(c0.w, c1.w)};
    *(uint4*)&Bs[0][grp][n4] = u0;
    *(uint4*)&Bs[0][8 + grp][n4] = u1;
  }
  gll16(pa0, &As[0][w * 32][0]);
  gll16(pa1, &As[0][w * 32 + 16][0]);
  __syncthreads();

  int cur = 0;
#pragma unroll 1
  for (int it = 0; it < (HF / NSPLIT) / BK; ++it) {
    const bool pf = (it + 1 < (HF / NSPLIT) / BK);
    float4 a0, a1, c0, c1;
    if (pf) {
      const size_t koff = (size_t)(it + 1) * BK * D;
      a0 = *(const float4*)(pB0 + koff);
      a1 = *(const float4*)(pB0 + koff + D);
      c0 = *(const float4*)(pB1 + koff);
      c1 = *(const float4*)(pB1 + koff + D);
      const int ko = (it + 1) * BK;
      gll16(pa0 + ko, &As[cur ^ 1][w * 32][0]);
      gll16(pa1 + ko, &As[cur ^ 1][w * 32 + 16][0]);
    }
    bf16x8 af[4], bfr[4];
#pragma unroll
    for (int mi = 0; mi < 4; ++mi)
      af[mi] = *(const bf16x8*)&As[cur][wm + mi * 16 + lr][kg * 8];
#pragma unroll
    for (int ni = 0; ni < 4; ++ni) {
      const int col = wn + ni * 16 + lr;
      uint4 tv;
      tv.x = Bs[cur][kg * 4 + 0][col];
      tv.y = Bs[cur][kg * 4 + 1][col];
      tv.z = Bs[cur][kg * 4 + 2][col];
      tv.w = Bs[cur][kg * 4 + 3][col];
      bfr[ni] = *(const bf16x8*)&tv;
    }
#pragma unroll
    for (int mi = 0; mi < 4; ++mi)
#pragma unroll
      for (int ni = 0; ni < 4; ++ni)
        acc[mi][ni] = __builtin_amdgcn_mfma_f32_16x16x32_bf16(af[mi], bfr[ni],
                                                              acc[mi][ni], 0, 0, 0);
    if (pf) {
      uint4 u0 = {cvtpk(a0.x, a1.x), cvtpk(a0.y, a1.y), cvtpk(a0.z, a1.z), cvtpk(a0.w, a1.w)};
      uint4 u1 = {cvtpk(c0.x, c1.x), cvtpk(c0.y, c1.y), cvtpk(c0.z, c1.z), cvtpk(c0.w, c1.w)};
      *(uint4*)&Bs[cur ^ 1][grp][n4] = u0;
      *(uint4*)&Bs[cur ^ 1][8 + grp][n4] = u1;
    }
    __syncthreads();
    cur ^= 1;
  }

#pragma unroll
  for (int mi = 0; mi < 4; ++mi)
#pragma unroll
    for (int ni = 0; ni < 4; ++ni) {
      f32x4 v = acc[mi][ni];
#pragma unroll
      for (int q = 0; q < 4; ++q) {
        const int slot = row0 + wm + mi * 16 + kg * 4 + q;
        if (slot < cnt)
          oe[((size_t)split * ACT_ROWS + gbase + slot) * D + jt + wn + ni * 16 + lr] =
              (ushort)bf16b(v[q]);
      }
    }
}

// ---- combine: out[t] = w0*(sum_s oe[s][r0] + b2[e0]) + w1*(sum_s oe[s][r1] + b2[e1]) ----
__global__ void combine_kernel(const ushort* __restrict__ oe,
                               const int* __restrict__ mr0, const int* __restrict__ mr1,
                               const float* __restrict__ mw0, const float* __restrict__ mw1,
                               const int* __restrict__ mi0, const int* __restrict__ mi1,
                               const float* __restrict__ b2, float* __restrict__ out) {
  const int t = blockIdx.x;
  const int l = threadIdx.x;  // 4 elems per thread
  const float w0 = mw0[t], w1 = mw1[t];
  const int r0 = mr0[t], r1 = mr1[t];
  float a0[4] = {0.f, 0.f, 0.f, 0.f}, a1[4] = {0.f, 0.f, 0.f, 0.f};
#pragma unroll
  for (int s = 0; s < NSPLIT; ++s) {
    uint2 u0 = *(const uint2*)(oe + ((size_t)s * ACT_ROWS + r0) * D + l * 4);
    uint2 u1 = *(const uint2*)(oe + ((size_t)s * ACT_ROWS + r1) * D + l * 4);
    a0[0] += __uint_as_float(u0.x << 16);
    a0[1] += __uint_as_float(u0.x & 0xffff0000u);
    a0[2] += __uint_as_float(u0.y << 16);
    a0[3] += __uint_as_float(u0.y & 0xffff0000u);
    a1[0] += __uint_as_float(u1.x << 16);
    a1[1] += __uint_as_float(u1.x & 0xffff0000u);
    a1[2] += __uint_as_float(u1.y << 16);
    a1[3] += __uint_as_float(u1.y & 0xffff0000u);
  }
  float4 c0 = ((const float4*)(b2 + (size_t)mi0[t] * D))[l];
  float4 c1 = ((const float4*)(b2 + (size_t)mi1[t] * D))[l];
  float4 r;
  r.x = w0 * (a0[0] + c0.x) + w1 * (a1[0] + c1.x);
  r.y = w0 * (a0[1] + c0.y) + w1 * (a1[1] + c1.y);
  r.z = w0 * (a0[2] + c0.z) + w1 * (a1[2] + c1.z);
  r.w = w0 * (a0[3] + c0.w) + w1 * (a1[3] + c1.w);
  ((float4*)(out + (size_t)t * D))[l] = r;
}

extern "C" void kernel_launch(void* const* d_in, const int* in_sizes, int n_in,
                              void* d_out, int out_size, void* d_ws, size_t ws_size,
                              hipStream_t stream) {
  const float* x  = (const float*)d_in[0];
  const float* gw = (const float*)d_in[1];
  const float* gb = (const float*)d_in[2];
  const float* w1 = (const float*)d_in[3];
  const float* b1 = (const float*)d_in[4];
  const float* w2 = (const float*)d_in[5];
  const float* b2 = (const float*)d_in[6];
  float* out = (float*)d_out;

  char* ws = (char*)d_ws;
  int*   counts   = (int*)(ws + 0);
  int*   basep    = (int*)(ws + 64);
  int*   rb_n     = (int*)(ws + 128);
  int*   rb_e     = (int*)(ws + 192);                       // 40 ints
  int*   rb_row0  = (int*)(ws + 384);                       // 40 ints
  int*   rb2_n    = (int*)(ws + 576);
  int*   rb2_e    = (int*)(ws + 640);                       // 24 ints
  int*   rb2_row0 = (int*)(ws + 768);                       // 24 ints
  int*   mi0      = (int*)(ws + 1024);
  int*   mi1      = (int*)(ws + 1024 + 1 * 8192);
  int*   mr0      = (int*)(ws + 1024 + 2 * 8192);
  int*   mr1      = (int*)(ws + 1024 + 3 * 8192);
  float* mw0      = (float*)(ws + 1024 + 4 * 8192);
  float* mw1      = (float*)(ws + 1024 + 5 * 8192);
  int*   list_tok = (int*)(ws + 1024 + 6 * 8192);           // 16384 B -> ends 66560
  ushort* xb      = (ushort*)(ws + 66560);                  // 4 MB
  ushort* act_buf = (ushort*)(ws + 4260864);                // 34.6 MB (4224 x 4096 bf16)
  ushort* oe      = (ushort*)(ws + 38863872);               // 34.6 MB (4 x 4224 x 1024 bf16)

  gate_kernel<<<S, 256, 0, stream>>>(x, gw, gb, xb, mi0, mi1, mw0, mw1);
  route_kernel<<<1, 1024, 0, stream>>>(mi0, mi1, counts, basep, list_tok, mr0, mr1,
                                       rb_e, rb_row0, rb_n, rb2_e, rb2_row0, rb2_n);
  gemm1_kernel<<<dim3(64, MAXRB2), 512, 0, stream>>>(xb, w1, b1, counts, basep, list_tok,
                                                     rb2_e, rb2_row0, rb2_n, act_buf);
  gemm2_kernel<<<dim3(8, MAXRB, NSPLIT), 256, 0, stream>>>(act_buf, w2, counts, basep,
                                                           rb_e, rb_row0, rb_n, oe);
  combine_kernel<<<S, 256, 0, stream>>>(oe, mr0, mr1, mw0, mw1, mi0, mi1, b2, out);
}

// Round 19
// 261.061 us; speedup vs baseline: 1.6499x; 1.0232x over previous
//
#include <hip/hip_runtime.h>
#include <hip/hip_bf16.h>

#define S 2048
#define D 1024
#define NE 8
#define HF 4096
#define HH 8192
#define BK 32
#define ACT_ROWS 4224  // 4096 + 128 pad
#define MAXRB 40       // 128-row blocks: 4096/128 + 8 - 1 = 39
#define MAXRB2 24      // 256-row blocks: 4096/256 + 8 - 1 = 23

typedef __attribute__((ext_vector_type(8))) __bf16 bf16x8;
typedef __attribute__((ext_vector_type(4))) float f32x4;

__device__ __forceinline__ unsigned cvtpk(float lo, float hi) {
  unsigned r;
  asm("v_cvt_pk_bf16_f32 %0, %1, %2" : "=v"(r) : "v"(lo), "v"(hi));
  return r;  // RNE, lo in low 16
}
__device__ __forceinline__ unsigned bf16b(float f) {
  unsigned b = __float_as_uint(f);
  return (b + 0x7fffu + ((b >> 16) & 1u)) >> 16;  // RNE fp32->bf16 (finite)
}
__device__ __forceinline__ void gll16(const ushort* g, ushort* l) {
  __builtin_amdgcn_global_load_lds(
      (const __attribute__((address_space(1))) void*)g,
      (__attribute__((address_space(3))) void*)l, 16, 0, 0);
}

// ------- gating + x->bf16 fused: one block (256 thr) per token -------
__global__ __launch_bounds__(256) void gate_kernel(
    const float* __restrict__ x, const float* __restrict__ gw,
    const float* __restrict__ gb, ushort* __restrict__ xb,
    int* __restrict__ mi0, int* __restrict__ mi1,
    float* __restrict__ mw0, float* __restrict__ mw1) {
  const int t = blockIdx.x;
  const int l = threadIdx.x;  // handles d = 4l..4l+3
  const float4 xv = ((const float4*)(x + (size_t)t * D))[l];
  uint2 wv = {cvtpk(xv.x, xv.y), cvtpk(xv.z, xv.w)};
  ((uint2*)(xb + (size_t)t * D))[l] = wv;

  float xa[4] = {xv.x, xv.y, xv.z, xv.w};
  float acc[NE];
#pragma unroll
  for (int e = 0; e < NE; ++e) acc[e] = 0.f;
  const float* g0 = gw + (size_t)(4 * l) * NE;
#pragma unroll
  for (int j = 0; j < 4; ++j)
#pragma unroll
    for (int e = 0; e < NE; ++e) acc[e] += xa[j] * g0[j * NE + e];
#pragma unroll
  for (int e = 0; e < NE; ++e) {
    float v = acc[e];
#pragma unroll
    for (int off = 32; off > 0; off >>= 1) v += __shfl_xor(v, off);
    acc[e] = v;
  }
  __shared__ float sm[4][NE];
  const int wid = l >> 6;
  if ((l & 63) == 0) {
#pragma unroll
    for (int e = 0; e < NE; ++e) sm[wid][e] = acc[e];
  }
  __syncthreads();
  if (l == 0) {
    float lg[NE];
#pragma unroll
    for (int e = 0; e < NE; ++e)
      lg[e] = sm[0][e] + sm[1][e] + sm[2][e] + sm[3][e] + gb[e];
    int i0 = 0; float m0 = lg[0];
#pragma unroll
    for (int e = 1; e < NE; ++e) if (lg[e] > m0) { m0 = lg[e]; i0 = e; }  // strict >: jax tie-break
    int i1 = -1; float m1 = -3.4e38f;
#pragma unroll
    for (int e = 0; e < NE; ++e) if (e != i0 && lg[e] > m1) { m1 = lg[e]; i1 = e; }
    float p = __expf(m1 - m0);
    float inv = 1.f / (1.f + p);
    mi0[t] = i0; mi1[t] = i1;
    mw0[t] = inv; mw1[t] = p * inv;
  }
}

// --- routing: counts + prefix + slots + compact rowblock tables (128 & 256 gran) ---
__global__ __launch_bounds__(1024) void route_kernel(
    const int* __restrict__ mi0, const int* __restrict__ mi1,
    int* __restrict__ counts, int* __restrict__ basep, int* __restrict__ list_tok,
    int* __restrict__ mr0, int* __restrict__ mr1,
    int* __restrict__ rb_e, int* __restrict__ rb_row0, int* __restrict__ rb_n,
    int* __restrict__ rb2_e, int* __restrict__ rb2_row0, int* __restrict__ rb2_n) {
  __shared__ int cnt[NE];
  __shared__ int cur[NE];
  const int t = threadIdx.x;
  if (t < NE) cnt[t] = 0;
  __syncthreads();
  const int e0a = mi0[t], e1a = mi1[t];
  const int e0b = mi0[t + 1024], e1b = mi1[t + 1024];
  atomicAdd(&cnt[e0a], 1); atomicAdd(&cnt[e1a], 1);
  atomicAdd(&cnt[e0b], 1); atomicAdd(&cnt[e1b], 1);
  __syncthreads();
  if (t == 0) {
    int s = 0;
#pragma unroll
    for (int e = 0; e < NE; ++e) { basep[e] = s; cur[e] = s; s += cnt[e]; }
    basep[NE] = s;
    int nrb = 0, nrb2 = 0;
    for (int e = 0; e < NE; ++e) {
      for (int r0 = 0; r0 < cnt[e]; r0 += 128) {
        rb_e[nrb] = e; rb_row0[nrb] = r0; ++nrb;
      }
      for (int r0 = 0; r0 < cnt[e]; r0 += 256) {
        rb2_e[nrb2] = e; rb2_row0[nrb2] = r0; ++nrb2;
      }
    }
    *rb_n = nrb;    // <= 39
    *rb2_n = nrb2;  // <= 23
  }
  if (t < NE) counts[t] = cnt[t];
  __syncthreads();
  int r;
  r = atomicAdd(&cur[e0a], 1); list_tok[r] = t; mr0[t] = r;
  r = atomicAdd(&cur[e1a], 1); list_tok[r] = t; mr1[t] = r;
  r = atomicAdd(&cur[e0b], 1); list_tok[r] = t + 1024; mr0[t + 1024] = r;
  r = atomicAdd(&cur[e1b], 1); list_tok[r] = t + 1024; mr1[t + 1024] = r;
}

// ---- GEMM1 + SwiGLU, BM=256, 8 waves: A via gll16, B fp32-direct via reg+LDS ----
__global__ __launch_bounds__(512) void gemm1_kernel(
    const ushort* __restrict__ xb, const float* __restrict__ w1,
    const float* __restrict__ b1, const int* __restrict__ counts,
    const int* __restrict__ basep, const int* __restrict__ list_tok,
    const int* __restrict__ rb2_e, const int* __restrict__ rb2_row0,
    const int* __restrict__ rb2_n, ushort* __restrict__ act_buf) {
  const int rb = blockIdx.y;
  if (rb >= *rb2_n) return;
  const int e = rb2_e[rb];
  const int row0 = rb2_row0[rb];
  const int cnt = counts[e];
  const int jt = blockIdx.x * 64;
  const float* __restrict__ Wf = w1 + (size_t)e * D * HH;  // [k=1024][n=8192] fp32
  const int gbase = basep[e];

  __shared__ ushort As[2][256][BK];   // 32 KB
  __shared__ unsigned Bs[2][32][68];  // 17.4 KB ([half*16+kp][n 0..63, +4 pad])

  const int tid = threadIdx.x;
  const int w = tid >> 6;   // 0..7
  const int i = tid & 63;

  // A staging: wave w stages rows w*32 .. w*32+31 (2x gll16)
  const int rA0 = w * 32 + (i >> 2);
  const int rA1 = rA0 + 16;
  int s0 = row0 + rA0; if (s0 >= cnt) s0 = cnt - 1;
  int s1 = row0 + rA1; if (s1 >= cnt) s1 = cnt - 1;
  const ushort* pa0 = xb + (size_t)list_tok[gbase + s0] * D + (i & 3) * 8;
  const ushort* pa1 = xb + (size_t)list_tok[gbase + s1] * D + (i & 3) * 8;

  // B staging: thread = (half, kpair kp, n4..n4+3); 2 coalesced float4 loads
  const int half = tid >> 8;        // 0: x-half, 1: gate-half
  const int kp = (tid >> 4) & 15;   // 0..15
  const int n4 = (tid & 15) * 4;    // 0..60
  const float* pB = Wf + (size_t)(2 * kp) * HH + jt + n4 + half * HF;

  const int wm = (w >> 1) * 64;     // 0,64,128,192
  const int wn = (w & 1) * 32;
  const int lr = i & 15;
  const int kg = i >> 4;            // 0..3

  f32x4 acc[2][4][2] = {};  // [half][mi][ni]

  // prologue: tile 0
  {
    float4 b0v = *(const float4*)(pB);
    float4 b1v = *(const float4*)(pB + HH);
    uint4 u = {cvtpk(b0v.x, b1v.x), cvtpk(b0v.y, b1v.y),
               cvtpk(b0v.z, b1v.z), cvtpk(b0v.w, b1v.w)};
    *(uint4*)&Bs[0][half * 16 + kp][n4] = u;
  }
  gll16(pa0, &As[0][w * 32][0]);
  gll16(pa1, &As[0][w * 32 + 16][0]);
  __syncthreads();

  int cur = 0;
#pragma unroll 1
  for (int it = 0; it < D / BK; ++it) {
    const bool pf = (it + 1 < D / BK);
    float4 b0v, b1v;
    if (pf) {  // issue-early: next-tile loads ride under the MFMA block
      const size_t koff = (size_t)(it + 1) * BK * HH;
      b0v = *(const float4*)(pB + koff);
      b1v = *(const float4*)(pB + koff + HH);
      const int ko = (it + 1) * BK;
      gll16(pa0 + ko, &As[cur ^ 1][w * 32][0]);
      gll16(pa1 + ko, &As[cur ^ 1][w * 32 + 16][0]);
    }
    bf16x8 af[4], bfr[2][2];
#pragma unroll
    for (int mi = 0; mi < 4; ++mi)
      af[mi] = *(const bf16x8*)&As[cur][wm + mi * 16 + lr][kg * 8];
#pragma unroll
    for (int h = 0; h < 2; ++h)
#pragma unroll
      for (int ni = 0; ni < 2; ++ni) {
        const int col = wn + ni * 16 + lr;
        uint4 tv;
        tv.x = Bs[cur][h * 16 + kg * 4 + 0][col];
        tv.y = Bs[cur][h * 16 + kg * 4 + 1][col];
        tv.z = Bs[cur][h * 16 + kg * 4 + 2][col];
        tv.w = Bs[cur][h * 16 + kg * 4 + 3][col];
        bfr[h][ni] = *(const bf16x8*)&tv;
      }
#pragma unroll
    for (int h = 0; h < 2; ++h)
#pragma unroll
      for (int mi = 0; mi < 4; ++mi)
#pragma unroll
        for (int ni = 0; ni < 2; ++ni)
          acc[h][mi][ni] = __builtin_amdgcn_mfma_f32_16x16x32_bf16(af[mi], bfr[h][ni],
                                                                   acc[h][mi][ni], 0, 0, 0);
    if (pf) {  // write-late into the freed buffer
      uint4 u = {cvtpk(b0v.x, b1v.x), cvtpk(b0v.y, b1v.y),
                 cvtpk(b0v.z, b1v.z), cvtpk(b0v.w, b1v.w)};
      *(uint4*)&Bs[cur ^ 1][half * 16 + kp][n4] = u;
    }
    __syncthreads();
    cur ^= 1;
  }

#pragma unroll
  for (int mi = 0; mi < 4; ++mi)
#pragma unroll
    for (int ni = 0; ni < 2; ++ni) {
      const int c = jt + wn + ni * 16 + lr;
      const float bx = b1[(size_t)e * HH + c];
      const float bg = b1[(size_t)e * HH + HF + c];
      f32x4 vx = acc[0][mi][ni];
      f32x4 vg = acc[1][mi][ni];
#pragma unroll
      for (int q = 0; q < 4; ++q) {
        const int slot = row0 + wm + mi * 16 + kg * 4 + q;
        if (slot < cnt) {
          float xv = vx[q] + bx;
          float g = vg[q] + bg;
          float a = g / (1.f + __expf(-g)) * xv;
          act_buf[(size_t)(gbase + slot) * HF + c] = (ushort)bf16b(a);
        }
      }
    }
}

// ---- GEMM2 (K-split 2): A via gll16, B fp32-direct; bf16 oe stores ----
__global__ __launch_bounds__(256) void gemm2_kernel(
    const ushort* __restrict__ act_buf, const float* __restrict__ w2,
    const int* __restrict__ counts, const int* __restrict__ basep,
    const int* __restrict__ rb_e, const int* __restrict__ rb_row0,
    const int* __restrict__ rb_n, ushort* __restrict__ oe) {
  const int rb = blockIdx.y;
  if (rb >= *rb_n) return;
  const int e = rb_e[rb];
  const int row0 = rb_row0[rb];
  const int cnt = counts[e];
  const int split = blockIdx.z;
  const int jt = blockIdx.x * 128;
  const float* __restrict__ Wf = w2 + (size_t)e * HF * D;  // [kf=4096][n=1024] fp32
  const int gbase = basep[e];
  const size_t kbase = (size_t)split * (HF / 2);

  __shared__ ushort As[2][128][BK];
  __shared__ unsigned Bs[2][16][132];  // [kp][n 0..127, +4 pad]

  const int tid = threadIdx.x;
  const int w = tid >> 6;
  const int i = tid & 63;

  const int rA0 = w * 32 + (i >> 2);
  const ushort* pa0 = act_buf + (size_t)(gbase + row0 + rA0) * HF + kbase + (i & 3) * 8;
  const ushort* pa1 = pa0 + (size_t)16 * HF;

  // B staging: thread = (kpairs grp & grp+8, n4..n4+3)
  const int grp = tid >> 5;          // 0..7
  const int n4 = (tid & 31) * 4;     // 0..124
  const float* pB0 = Wf + (kbase + 2 * grp) * D + jt + n4;       // kp = grp
  const float* pB1 = pB0 + (size_t)16 * D;                        // kp = grp + 8

  const int wm = (w >> 1) * 64;
  const int wn = (w & 1) * 64;
  const int lr = i & 15;
  const int kg = i >> 4;

  f32x4 acc[4][4] = {};

  {
    float4 a0 = *(const float4*)(pB0);
    float4 a1 = *(const float4*)(pB0 + D);
    float4 c0 = *(const float4*)(pB1);
    float4 c1 = *(const float4*)(pB1 + D);
    uint4 u0 = {cvtpk(a0.x, a1.x), cvtpk(a0.y, a1.y), cvtpk(a0.z, a1.z), cvtpk(a0.w, a1.w)};
    uint4 u1 = {cvtpk(c0.x, c1.x), cvtpk(c0.y, c1.y), cvtpk(c0.z, c1.z), cvtpk(c0.w, c1.w)};
    *(uint4*)&Bs[0][grp][n4] = u0;
    *(uint4*)&Bs[0][8 + grp][n4] = u1;
  }
  gll16(pa0, &As[0][w * 32][0]);
  gll16(pa1, &As[0][w * 32 + 16][0]);
  __syncthreads();

  int cur = 0;
#pragma unroll 1
  for (int it = 0; it < (HF / 2) / BK; ++it) {
    const bool pf = (it + 1 < (HF / 2) / BK);
    float4 a0, a1, c0, c1;
    if (pf) {
      const size_t koff = (size_t)(it + 1) * BK * D;
      a0 = *(const float4*)(pB0 + koff);
      a1 = *(const float4*)(pB0 + koff + D);
      c0 = *(const float4*)(pB1 + koff);
      c1 = *(const float4*)(pB1 + koff + D);
      const int ko = (it + 1) * BK;
      gll16(pa0 + ko, &As[cur ^ 1][w * 32][0]);
      gll16(pa1 + ko, &As[cur ^ 1][w * 32 + 16][0]);
    }
    bf16x8 af[4], bfr[4];
#pragma unroll
    for (int mi = 0; mi < 4; ++mi)
      af[mi] = *(const bf16x8*)&As[cur][wm + mi * 16 + lr][kg * 8];
#pragma unroll
    for (int ni = 0; ni < 4; ++ni) {
      const int col = wn + ni * 16 + lr;
      uint4 tv;
      tv.x = Bs[cur][kg * 4 + 0][col];
      tv.y = Bs[cur][kg * 4 + 1][col];
      tv.z = Bs[cur][kg * 4 + 2][col];
      tv.w = Bs[cur][kg * 4 + 3][col];
      bfr[ni] = *(const bf16x8*)&tv;
    }
#pragma unroll
    for (int mi = 0; mi < 4; ++mi)
#pragma unroll
      for (int ni = 0; ni < 4; ++ni)
        acc[mi][ni] = __builtin_amdgcn_mfma_f32_16x16x32_bf16(af[mi], bfr[ni],
                                                              acc[mi][ni], 0, 0, 0);
    if (pf) {
      uint4 u0 = {cvtpk(a0.x, a1.x), cvtpk(a0.y, a1.y), cvtpk(a0.z, a1.z), cvtpk(a0.w, a1.w)};
      uint4 u1 = {cvtpk(c0.x, c1.x), cvtpk(c0.y, c1.y), cvtpk(c0.z, c1.z), cvtpk(c0.w, c1.w)};
      *(uint4*)&Bs[cur ^ 1][grp][n4] = u0;
      *(uint4*)&Bs[cur ^ 1][8 + grp][n4] = u1;
    }
    __syncthreads();
    cur ^= 1;
  }

#pragma unroll
  for (int mi = 0; mi < 4; ++mi)
#pragma unroll
    for (int ni = 0; ni < 4; ++ni) {
      f32x4 v = acc[mi][ni];
#pragma unroll
      for (int q = 0; q < 4; ++q) {
        const int slot = row0 + wm + mi * 16 + kg * 4 + q;
        if (slot < cnt)
          oe[((size_t)split * ACT_ROWS + gbase + slot) * D + jt + wn + ni * 16 + lr] =
              (ushort)bf16b(v[q]);
      }
    }
}

// ---- combine: out[t] = w0*(sum_s oe[s][r0] + b2[e0]) + w1*(sum_s oe[s][r1] + b2[e1]) ----
__global__ void combine_kernel(const ushort* __restrict__ oe,
                               const int* __restrict__ mr0, const int* __restrict__ mr1,
                               const float* __restrict__ mw0, const float* __restrict__ mw1,
                               const int* __restrict__ mi0, const int* __restrict__ mi1,
                               const float* __restrict__ b2, float* __restrict__ out) {
  const int t = blockIdx.x;
  const int l = threadIdx.x;  // 4 elems per thread
  const float w0 = mw0[t], w1 = mw1[t];
  const int r0 = mr0[t], r1 = mr1[t];
  float a0[4] = {0.f, 0.f, 0.f, 0.f}, a1[4] = {0.f, 0.f, 0.f, 0.f};
#pragma unroll
  for (int s = 0; s < 2; ++s) {
    uint2 u0 = *(const uint2*)(oe + ((size_t)s * ACT_ROWS + r0) * D + l * 4);
    uint2 u1 = *(const uint2*)(oe + ((size_t)s * ACT_ROWS + r1) * D + l * 4);
    a0[0] += __uint_as_float(u0.x << 16);
    a0[1] += __uint_as_float(u0.x & 0xffff0000u);
    a0[2] += __uint_as_float(u0.y << 16);
    a0[3] += __uint_as_float(u0.y & 0xffff0000u);
    a1[0] += __uint_as_float(u1.x << 16);
    a1[1] += __uint_as_float(u1.x & 0xffff0000u);
    a1[2] += __uint_as_float(u1.y << 16);
    a1[3] += __uint_as_float(u1.y & 0xffff0000u);
  }
  float4 c0 = ((const float4*)(b2 + (size_t)mi0[t] * D))[l];
  float4 c1 = ((const float4*)(b2 + (size_t)mi1[t] * D))[l];
  float4 r;
  r.x = w0 * (a0[0] + c0.x) + w1 * (a1[0] + c1.x);
  r.y = w0 * (a0[1] + c0.y) + w1 * (a1[1] + c1.y);
  r.z = w0 * (a0[2] + c0.z) + w1 * (a1[2] + c1.z);
  r.w = w0 * (a0[3] + c0.w) + w1 * (a1[3] + c1.w);
  ((float4*)(out + (size_t)t * D))[l] = r;
}

extern "C" void kernel_launch(void* const* d_in, const int* in_sizes, int n_in,
                              void* d_out, int out_size, void* d_ws, size_t ws_size,
                              hipStream_t stream) {
  const float* x  = (const float*)d_in[0];
  const float* gw = (const float*)d_in[1];
  const float* gb = (const float*)d_in[2];
  const float* w1 = (const float*)d_in[3];
  const float* b1 = (const float*)d_in[4];
  const float* w2 = (const float*)d_in[5];
  const float* b2 = (const float*)d_in[6];
  float* out = (float*)d_out;

  char* ws = (char*)d_ws;
  int*   counts   = (int*)(ws + 0);
  int*   basep    = (int*)(ws + 64);
  int*   rb_n     = (int*)(ws + 128);
  int*   rb_e     = (int*)(ws + 192);                       // 40 ints
  int*   rb_row0  = (int*)(ws + 384);                       // 40 ints
  int*   rb2_n    = (int*)(ws + 576);
  int*   rb2_e    = (int*)(ws + 640);                       // 24 ints
  int*   rb2_row0 = (int*)(ws + 768);                       // 24 ints
  int*   mi0      = (int*)(ws + 1024);
  int*   mi1      = (int*)(ws + 1024 + 1 * 8192);
  int*   mr0      = (int*)(ws + 1024 + 2 * 8192);
  int*   mr1      = (int*)(ws + 1024 + 3 * 8192);
  float* mw0      = (float*)(ws + 1024 + 4 * 8192);
  float* mw1      = (float*)(ws + 1024 + 5 * 8192);
  int*   list_tok = (int*)(ws + 1024 + 6 * 8192);           // 16384 B -> ends 66560
  ushort* xb      = (ushort*)(ws + 66560);                  // 4 MB
  ushort* act_buf = (ushort*)(ws + 4260864);                // 34.6 MB (4224 x 4096 bf16)
  ushort* oe      = (ushort*)(ws + 38863872);               // 17.3 MB (2 x 4224 x 1024 bf16)

  gate_kernel<<<S, 256, 0, stream>>>(x, gw, gb, xb, mi0, mi1, mw0, mw1);
  route_kernel<<<1, 1024, 0, stream>>>(mi0, mi1, counts, basep, list_tok, mr0, mr1,
                                       rb_e, rb_row0, rb_n, rb2_e, rb2_row0, rb2_n);
  gemm1_kernel<<<dim3(64, MAXRB2), 512, 0, stream>>>(xb, w1, b1, counts, basep, list_tok,
                                                     rb2_e, rb2_row0, rb2_n, act_buf);
  gemm2_kernel<<<dim3(8, MAXRB, 2), 256, 0, stream>>>(act_buf, w2, counts, basep,
                                                      rb_e, rb_row0, rb_n, oe);
  combine_kernel<<<S, 256, 0, stream>>>(oe, mr0, mr1, mw0, mw1, mi0, mi1, b2, out);
}